// Round 1
// baseline (632.424 us; speedup 1.0000x reference)
//
#include <hip/hip_runtime.h>
#include <math.h>

// Problem constants (B=16, T=4096, D=64, K=1024)
#define NROWS    65536      // B*T
#define DD       64
#define KK       1024
#define ZQ_ELEMS 4194304    // NROWS*DD
#define LOSS_OFF 4194304
#define IDX_OFF  4194305    // idx written as float32 (harness reads flat fp32)

// Replicate numpy pairwise_sum (n=64 <= PW_BLOCKSIZE path: 8 accumulators,
// sequential adds, fixed combine tree) over fl(v[i]^2). contract(off) so the
// square is rounded to fp32 BEFORE the add (numpy materializes the temp
// array v*v first) — hipcc's default ffp-contract=fast would fuse mul+add
// and change the rounding, breaking bit-match with the np reference.
__device__ __forceinline__ float np_sumsq64(const float* v) {
#pragma clang fp contract(off)
    float r[8];
#pragma unroll
    for (int j = 0; j < 8; ++j) r[j] = v[j] * v[j];
#pragma unroll
    for (int i = 8; i < 64; i += 8) {
#pragma unroll
        for (int j = 0; j < 8; ++j) r[j] += v[i + j] * v[i + j];
    }
    return ((r[0] + r[1]) + (r[2] + r[3])) + ((r[4] + r[5]) + (r[6] + r[7]));
}

// Kernel 1: per-code norms ||e_k||^2 (numpy summation order) + zero the
// fp64 loss accumulator (d_ws is re-poisoned to 0xAA before every launch).
__global__ void vq_norms(const float* __restrict__ emb,
                         float* __restrict__ bn,
                         double* __restrict__ acc) {
    const int k = blockIdx.x * blockDim.x + threadIdx.x;
    if (k == 0) *acc = 0.0;
    if (k >= KK) return;
    float e[DD];
    const float* ep = emb + (size_t)k * DD;
#pragma unroll
    for (int d = 0; d < DD; d += 4) {
        const float4 v = *reinterpret_cast<const float4*>(ep + d);
        e[d] = v.x; e[d + 1] = v.y; e[d + 2] = v.z; e[d + 3] = v.w;
    }
    bn[k] = np_sumsq64(e);
}

// Kernel 2: one thread per row. dist_k = fl(fl(a + b_k) - 2*dot_k) with
// dot_k a sequential fmaf chain over d (matches BLAS sgemm k-order FMA
// accumulation; 2*dot is exact so fmaf(-2,dot,t) == fl(t - fl(2*dot))).
// Argmin scans k ascending with strict < (numpy first-index tie-break).
__global__ __launch_bounds__(256) void vq_main(
        const float* __restrict__ z, const float* __restrict__ emb,
        const float* __restrict__ bn, float* __restrict__ out,
        double* __restrict__ acc) {
    const int row = blockIdx.x * 256 + threadIdx.x;

    float zr[DD];
    const float* zp = z + (size_t)row * DD;
#pragma unroll
    for (int d = 0; d < DD; d += 4) {
        const float4 v = *reinterpret_cast<const float4*>(zp + d);
        zr[d] = v.x; zr[d + 1] = v.y; zr[d + 2] = v.z; zr[d + 3] = v.w;
    }
    const float a = np_sumsq64(zr);   // ||z_row||^2, numpy bit-order

    float best = 3.402823466e+38f;
    int bid = 0;
    // k unrolled x4: 4 independent 64-deep fmaf chains -> ILP hides the
    // 4-cycle FMA latency at this grid's ~1 wave/SIMD occupancy.
    for (int k = 0; k < KK; k += 4) {
        const float* e0 = emb + (size_t)k * DD;
        float dot0 = 0.f, dot1 = 0.f, dot2 = 0.f, dot3 = 0.f;
#pragma unroll
        for (int d = 0; d < DD; ++d) {
            dot0 = fmaf(zr[d], e0[d], dot0);
            dot1 = fmaf(zr[d], e0[DD + d], dot1);
            dot2 = fmaf(zr[d], e0[2 * DD + d], dot2);
            dot3 = fmaf(zr[d], e0[3 * DD + d], dot3);
        }
        const float t0 = a + bn[k];
        const float t1 = a + bn[k + 1];
        const float t2 = a + bn[k + 2];
        const float t3 = a + bn[k + 3];
        const float s0 = fmaf(-2.f, dot0, t0);
        const float s1 = fmaf(-2.f, dot1, t1);
        const float s2 = fmaf(-2.f, dot2, t2);
        const float s3 = fmaf(-2.f, dot3, t3);
        if (s0 < best) { best = s0; bid = k; }
        if (s1 < best) { best = s1; bid = k + 1; }
        if (s2 < best) { best = s2; bid = k + 2; }
        if (s3 < best) { best = s3; bid = k + 3; }
    }

    // Epilogue: z_q = z + (e - z)  (ref's straight-through form, NOT just e),
    // loss terms (e - z)^2 in fp32 then fp64 accumulate.
    const float* ep = emb + (size_t)bid * DD;
    float* op = out + (size_t)row * DD;
    double s = 0.0;
#pragma unroll
    for (int d = 0; d < DD; d += 4) {
        float4 q;
        float df0 = ep[d]     - zr[d];
        float df1 = ep[d + 1] - zr[d + 1];
        float df2 = ep[d + 2] - zr[d + 2];
        float df3 = ep[d + 3] - zr[d + 3];
        q.x = zr[d] + df0; q.y = zr[d + 1] + df1;
        q.z = zr[d + 2] + df2; q.w = zr[d + 3] + df3;
        *reinterpret_cast<float4*>(op + d) = q;
        float a0 = df0 * df0, a1 = df1 * df1, a2 = df2 * df2, a3 = df3 * df3;
        s += (double)a0; s += (double)a1; s += (double)a2; s += (double)a3;
    }
    out[IDX_OFF + row] = (float)bid;

    // Block reduction -> one fp64 atomic per block.
#pragma unroll
    for (int off = 32; off > 0; off >>= 1) s += __shfl_down(s, off, 64);
    __shared__ double wsum[4];
    const int lane = threadIdx.x & 63, w = threadIdx.x >> 6;
    if (lane == 0) wsum[w] = s;
    __syncthreads();
    if (threadIdx.x == 0) {
        atomicAdd(acc, (wsum[0] + wsum[1]) + (wsum[2] + wsum[3]));
    }
}

// Kernel 3: loss = sum_b 1.25 * mean_b = 1.25 * S_total / (T*D)
__global__ void vq_finalize(const double* __restrict__ acc,
                            float* __restrict__ out) {
    out[LOSS_OFF] = (float)((1.25 * *acc) / 262144.0);
}

extern "C" void kernel_launch(void* const* d_in, const int* in_sizes, int n_in,
                              void* d_out, int out_size, void* d_ws, size_t ws_size,
                              hipStream_t stream) {
    const float* z   = (const float*)d_in[0];   // [16,4096,64] fp32
    const float* emb = (const float*)d_in[1];   // [1024,64] fp32
    float* out = (float*)d_out;                 // zq | loss | idx (flat fp32)

    float*  bn  = (float*)d_ws;                     // 1024 floats
    double* acc = (double*)((char*)d_ws + 4096);    // fp64 loss accumulator

    vq_norms<<<dim3(KK / 256), dim3(256), 0, stream>>>(emb, bn, acc);
    vq_main<<<dim3(NROWS / 256), dim3(256), 0, stream>>>(z, emb, bn, out, acc);
    vq_finalize<<<dim3(1), dim3(1), 0, stream>>>(acc, out);
}

// Round 2
// 244.250 us; speedup vs baseline: 2.5893x; 2.5893x over previous
//
#include <hip/hip_runtime.h>
#include <math.h>

// Problem constants (B=16, T=4096, D=64, K=1024)
#define NROWS    65536      // B*T
#define DD       64
#define KK       1024
#define LOSS_OFF 4194304
#define IDX_OFF  4194305    // idx written as float32 (harness reads flat fp32)

// Replicate numpy pairwise_sum (n=64: 8 accumulators, sequential adds, fixed
// combine tree) over fl(v[i]^2). contract(off) so the square is rounded to
// fp32 BEFORE the add (numpy materializes v*v first) — verified bit-exact
// (round 1 absmax 0.0). Do not touch.
__device__ __forceinline__ float np_sumsq64(const float* v) {
#pragma clang fp contract(off)
    float r[8];
#pragma unroll
    for (int j = 0; j < 8; ++j) r[j] = v[j] * v[j];
#pragma unroll
    for (int i = 8; i < 64; i += 8) {
#pragma unroll
        for (int j = 0; j < 8; ++j) r[j] += v[i + j] * v[i + j];
    }
    return ((r[0] + r[1]) + (r[2] + r[3])) + ((r[4] + r[5]) + (r[6] + r[7]));
}

// Kernel 1: per-code norms ||e_k||^2 (numpy order) + zero fp64 loss acc.
__global__ void vq_norms(const float* __restrict__ emb,
                         float* __restrict__ bn,
                         double* __restrict__ acc) {
    const int k = blockIdx.x * blockDim.x + threadIdx.x;
    if (k == 0) *acc = 0.0;
    if (k >= KK) return;
    float e[DD];
    const float* ep = emb + (size_t)k * DD;
#pragma unroll
    for (int d = 0; d < DD; d += 4) {
        const float4 v = *reinterpret_cast<const float4*>(ep + d);
        e[d] = v.x; e[d + 1] = v.y; e[d + 2] = v.z; e[d + 3] = v.w;
    }
    bn[k] = np_sumsq64(e);
}

// Kernel 2: block = 4 waves over the SAME 64 rows; wave w scans code slice
// [w*256, (w+1)*256). Each lane owns one row (zr in VGPRs — launch_bounds
// (256,2) gives a 256-VGPR budget so the 64-float row does NOT spill; the
// round-1 default budget of 64 VGPRs spilled zr to scratch = 47 GB writes).
// dist chain is bit-identical to round 1 (absmax 0.0): t = a + bn[k];
// s = fmaf(-2, dot, t); dot = ascending-d fmaf chain.
__global__ __launch_bounds__(256, 2) void vq_main(
        const float* __restrict__ z, const float* __restrict__ emb,
        const float* __restrict__ bn, float* __restrict__ out,
        double* __restrict__ acc) {
    const int tid  = threadIdx.x;
    const int lane = tid & 63;
    // readfirstlane -> compiler-visibly wave-uniform slice id, so e/bn
    // addresses scalarize (s_load through sKcache, not per-lane VMEM).
    const int wv   = __builtin_amdgcn_readfirstlane(tid) >> 6;   // 0..3
    const int row  = blockIdx.x * 64 + lane;

    float zr[DD];
    const float* zp = z + (size_t)row * DD;
#pragma unroll
    for (int d = 0; d < DD; d += 4) {
        const float4 v = *reinterpret_cast<const float4*>(zp + d);
        zr[d] = v.x; zr[d + 1] = v.y; zr[d + 2] = v.z; zr[d + 3] = v.w;
    }
    const float a = np_sumsq64(zr);   // ||z_row||^2, numpy bit-order

    float best = 3.402823466e+38f;
    int bid = 0;
    const int k0 = wv * (KK / 4);
    // 4 codes in flight: 4 independent 64-deep fmaf chains (dep distance
    // 8 cyc > 4 cyc FMA latency) — full VALU issue rate even at low occupancy.
    for (int k = k0; k < k0 + KK / 4; k += 4) {
        const float* e0 = emb + (size_t)k * DD;
        float dot0 = 0.f, dot1 = 0.f, dot2 = 0.f, dot3 = 0.f;
#pragma unroll
        for (int d = 0; d < DD; ++d) {
            dot0 = fmaf(zr[d], e0[d], dot0);
            dot1 = fmaf(zr[d], e0[DD + d], dot1);
            dot2 = fmaf(zr[d], e0[2 * DD + d], dot2);
            dot3 = fmaf(zr[d], e0[3 * DD + d], dot3);
        }
        const float t0 = a + bn[k];
        const float t1 = a + bn[k + 1];
        const float t2 = a + bn[k + 2];
        const float t3 = a + bn[k + 3];
        const float s0 = fmaf(-2.f, dot0, t0);
        const float s1 = fmaf(-2.f, dot1, t1);
        const float s2 = fmaf(-2.f, dot2, t2);
        const float s3 = fmaf(-2.f, dot3, t3);
        if (s0 < best) { best = s0; bid = k; }
        if (s1 < best) { best = s1; bid = k + 1; }
        if (s2 < best) { best = s2; bid = k + 2; }
        if (s3 < best) { best = s3; bid = k + 3; }
    }

    // Cross-slice argmin combine. Slices hold ascending k-ranges; iterating
    // s ascending with strict < reproduces numpy's global first-index
    // tie-break exactly (within-slice scan is already first-index).
    __shared__ float sbest[4][64];
    __shared__ int   sbid[4][64];
    sbest[wv][lane] = best;
    sbid[wv][lane]  = bid;
    __syncthreads();
    if (wv != 0) return;
#pragma unroll
    for (int s = 1; s < 4; ++s) {
        const float b2 = sbest[s][lane];
        const int   i2 = sbid[s][lane];
        if (b2 < best) { best = b2; bid = i2; }
    }

    // Epilogue (wave 0 only; zr still live in its registers).
    const float* ep = emb + (size_t)bid * DD;
    float* op = out + (size_t)row * DD;
    double sac = 0.0;
#pragma unroll
    for (int d = 0; d < DD; d += 4) {
        const float4 e4 = *reinterpret_cast<const float4*>(ep + d);
        const float df0 = e4.x - zr[d];
        const float df1 = e4.y - zr[d + 1];
        const float df2 = e4.z - zr[d + 2];
        const float df3 = e4.w - zr[d + 3];
        float4 q;
        q.x = zr[d] + df0;     q.y = zr[d + 1] + df1;
        q.z = zr[d + 2] + df2; q.w = zr[d + 3] + df3;
        *reinterpret_cast<float4*>(op + d) = q;
        sac += (double)(df0 * df0); sac += (double)(df1 * df1);
        sac += (double)(df2 * df2); sac += (double)(df3 * df3);
    }
    out[IDX_OFF + row] = (float)bid;

#pragma unroll
    for (int off = 32; off > 0; off >>= 1) sac += __shfl_down(sac, off, 64);
    if (lane == 0) atomicAdd(acc, sac);
}

// Kernel 3: loss = 1.25 * S_total / (T*D)
__global__ void vq_finalize(const double* __restrict__ acc,
                            float* __restrict__ out) {
    out[LOSS_OFF] = (float)((1.25 * *acc) / 262144.0);
}

extern "C" void kernel_launch(void* const* d_in, const int* in_sizes, int n_in,
                              void* d_out, int out_size, void* d_ws, size_t ws_size,
                              hipStream_t stream) {
    const float* z   = (const float*)d_in[0];   // [16,4096,64] fp32
    const float* emb = (const float*)d_in[1];   // [1024,64] fp32
    float* out = (float*)d_out;                 // zq | loss | idx (flat fp32)

    float*  bn  = (float*)d_ws;                     // 1024 floats
    double* acc = (double*)((char*)d_ws + 4096);    // fp64 loss accumulator

    vq_norms<<<dim3(KK / 256), dim3(256), 0, stream>>>(emb, bn, acc);
    vq_main<<<dim3(NROWS / 64), dim3(256), 0, stream>>>(z, emb, bn, out, acc);
    vq_finalize<<<dim3(1), dim3(1), 0, stream>>>(acc, out);
}